// Round 5
// baseline (356.633 us; speedup 1.0000x reference)
//
#include <hip/hip_runtime.h>

#define CH    128
#define IMG   56
#define PADW  58
#define HWSZ  3136
#define NPIX  200704        // 64*3136
#define WELEMS 147456       // 128*128*9
#define BNEPS 1e-5f
#define PADB  430592        // 58*58*128, one halo-padded i8 image
#define YOFF  27557888u     // y1 i16 NHWC in d_out
#define Y2OFF_B 51380224u   // Plan B: y2 in d_out top half
#define WQ1OFF_B 78938112u  // Plan B: wq1 parked above y1
#define IMGB  802816u       // one image of y (HWSZ*CH*2)

// conv-v4 geometry: 224 output pixels (4 image rows) per block, 4 waves
#define BPIX   224
#define NBLK   (NPIX / BPIX)        // 896
#define STRIPB 44544                // 6 padded rows * 58 * 128
#define STRIPC 2784                 // 16B chunks in strip
#define REDOFF 44544                // stats reduction scratch (after strip)
#define SMEMC  45568                // k_conv smem: strip + 1K red
#define SMEM63 58368                // out63 smem: strip + f16 tile[128][228]

typedef float f32x4 __attribute__((ext_vector_type(4)));
typedef int   i32x4 __attribute__((ext_vector_type(4)));
typedef short short8 __attribute__((ext_vector_type(8)));
typedef _Float16 f16;

__device__ __forceinline__ void async16(const void* g, void* l) {
  __builtin_amdgcn_global_load_lds(
      (const __attribute__((address_space(1))) unsigned int*)g,
      (__attribute__((address_space(3))) unsigned int*)l, 16, 0, 0);
}
// inline BN-param compute (per-block, channels 0..127 -> bnpS[0..255])
__device__ __forceinline__ void bn_inline(int lin, const float* stats, const unsigned* abits,
                                          const float* g, const float* b, float* bnpS) {
  if (lin < 128) {
    const float inv = 1.f / (float)NPIX;
    float gs   = (__uint_as_float(*abits) + 1e-12f) * (1.f / 105.f);
    float mean = stats[lin] * inv;
    float var  = fmaxf(stats[CH + lin] * inv - mean * mean, 0.f);
    float sc   = g[lin] * gs * rsqrtf(gs * gs * var + BNEPS);
    bnpS[lin]      = sc;
    bnpS[CH + lin] = b[lin] - sc * mean;
  }
}
// zero the 29,184-byte halo of one padded image (1824 16B chunks, 256 threads)
__device__ __forceinline__ void halo_zero(unsigned char* qb, int lin) {
  for (int i = lin; i < 1824; i += 256) {
    size_t off;
    if (i < 464)      off = (size_t)i * 16;                                  // row 0
    else if (i < 928) off = (size_t)57 * PADW * 128 + (size_t)(i - 464) * 16; // row 57
    else {
      int j = i - 928, loc = j >> 3, sub = j & 7;
      int row = 1 + (loc >> 1), col = (loc & 1) ? 57 : 0;
      off = ((size_t)row * PADW + col) * 128 + (size_t)sub * 16;
    }
    *(uint4*)(qb + off) = (uint4){0u, 0u, 0u, 0u};
  }
}

// ---------------- weight absmax ----------------
__global__ void k_wmax(const float* __restrict__ w1, const float* __restrict__ w2,
                       unsigned* __restrict__ alpha_bits) {
  int idx = blockIdx.x * 256 + threadIdx.x;
  float m1 = 0.f, m2 = 0.f;
  for (int i = idx; i < WELEMS; i += gridDim.x * 256) {
    m1 = fmaxf(m1, fabsf(w1[i]));
    m2 = fmaxf(m2, fabsf(w2[i]));
  }
#pragma unroll
  for (int off = 32; off > 0; off >>= 1) {
    m1 = fmaxf(m1, __shfl_xor(m1, off));
    m2 = fmaxf(m2, __shfl_xor(m2, off));
  }
  __shared__ float s1[4], s2[4];
  int wave = threadIdx.x >> 6;
  if ((threadIdx.x & 63) == 0) { s1[wave] = m1; s2[wave] = m2; }
  __syncthreads();
  if (threadIdx.x == 0) {
    m1 = fmaxf(fmaxf(s1[0], s1[1]), fmaxf(s1[2], s1[3]));
    m2 = fmaxf(fmaxf(s2[0], s2[1]), fmaxf(s2[2], s2[3]));
    atomicMax(&alpha_bits[0], __float_as_uint(m1));
    atomicMax(&alpha_bits[1], __float_as_uint(m2));
  }
}

// ---------------- weight quantize to int8 (-7..7), OIHW -> [kk][co][ci] ----------------
__global__ void k_wquant(const float* __restrict__ w1, const float* __restrict__ w2,
                         const unsigned* __restrict__ alpha_bits,
                         unsigned char* __restrict__ wq1, unsigned char* __restrict__ wq2) {
  int idx = blockIdx.x * 256 + threadIdx.x;
  int t = idx >= WELEMS;
  int j = t ? idx - WELEMS : idx;
  int kk  = j >> 14;
  int rem = j & 16383;
  int co = rem >> 7, ci = rem & 127;
  float alpha = __uint_as_float(alpha_bits[t]) + 1e-12f;
  float v  = (t ? w2 : w1)[co * 1152 + ci * 9 + kk];
  float wc = fminf(fmaxf(v / alpha, -1.f), 1.f);
  int q = (int)rintf(wc * 7.f);
  (t ? wq2 : wq1)[j] = (unsigned char)(q & 0xFF);   // two's-complement int8
}

// ---------------- act quant v2: full-channel tile, wide NHWC stores ----------------
__global__ void k_actq(const float* __restrict__ x, unsigned char* __restrict__ qx) {
  __shared__ float tile[128][33];
  int n = blockIdx.z, p0 = blockIdx.x * 32;
  int tx = threadIdx.x, ty = threadIdx.y, lin = ty * 32 + tx;
  unsigned char* qb = qx + (size_t)n * PADB;
  if (blockIdx.x == 0) halo_zero(qb, lin);
  const float* xs = x + (size_t)n * CH * HWSZ;
#pragma unroll
  for (int r = 0; r < 16; ++r) {
    int c = ty + r * 8;
    float v = xs[(size_t)c * HWSZ + p0 + tx];       // coalesced along p
    v = fminf(fmaxf(v, 0.f), 1.f);                  // kills NaN too
    tile[c][tx] = rintf(v * 15.f);
  }
  __syncthreads();
  int p = lin >> 3, q8 = lin & 7;
  int pl = p0 + p;
  int h = pl / IMG, w = pl - h * IMG;
  unsigned u[4];
#pragma unroll
  for (int k = 0; k < 4; ++k) {
    unsigned b0 = (unsigned)(int)tile[q8 * 16 + k * 4 + 0][p];
    unsigned b1 = (unsigned)(int)tile[q8 * 16 + k * 4 + 1][p];
    unsigned b2 = (unsigned)(int)tile[q8 * 16 + k * 4 + 2][p];
    unsigned b3 = (unsigned)(int)tile[q8 * 16 + k * 4 + 3][p];
    u[k] = b0 | (b1 << 8) | (b2 << 16) | (b3 << 24);
  }
  *(uint4*)(qb + ((size_t)(h + 1) * PADW + (w + 1)) * 128 + q8 * 16) =
      (uint4){u[0], u[1], u[2], u[3]};
}

// ============ conv core v4: strip-resident A in LDS, B direct L2->VGPR, ZERO K-loop barriers ====
// B tile (16 KB/kk) is identical across all 896 blocks -> L2-resident. Loading it
// global->reg removes the per-kk global_load_lds queue, its vmcnt(0) drains, and
// all 18 barriers. Only barrier left: after the strip prologue. LDS reads drop
// 22->14 per wave/kk. 4 waves/block, launch_bounds(256,2) -> 2 waves/SIMD, 256 VGPR
// budget (acc 112 + af 28 + bf 16 fits; scheduler can hoist B loads a phase early).
#define CONV_SETUP2                                                              \
  const int tid  = threadIdx.x;                                                  \
  const int lane = tid & 63;                                                     \
  const int quad = lane >> 4, lrow = lane & 15;                                  \
  const int m_base = ((tid >> 6) >> 1) * 112, n_base = ((tid >> 6) & 1) * 64;    \
  int sbase[7];                                                                  \
  _Pragma("unroll")                                                              \
  for (int mi = 0; mi < 7; ++mi) {                                               \
    int row = m_base + mi * 16 + lrow;                                           \
    sbase[mi] = (row / 56) * 58 + (row % 56);                                    \
  }                                                                              \
  int bgoff[4];                                                                  \
  _Pragma("unroll")                                                              \
  for (int ni = 0; ni < 4; ++ni)                                                 \
    bgoff[ni] = (n_base + ni * 16 + lrow) * 128 + (quad << 4);                   \
  i32x4 acc[7][4];                                                               \
  _Pragma("unroll")                                                              \
  for (int mi = 0; mi < 7; ++mi)                                                 \
    _Pragma("unroll")                                                            \
    for (int ni = 0; ni < 4; ++ni) acc[mi][ni] = (i32x4){0, 0, 0, 0};

// prologue: stage halo strip (linear LDS dest, inverse-swizzled source), ONE barrier
#define CONV_STAGE_PRO(STRIPSRC)                                                 \
  _Pragma("unroll")                                                              \
  for (int it = 0; it < 11; ++it) {                                              \
    int u = it * 256 + tid;                                                      \
    if (u < STRIPC) {                                                            \
      int s = u >> 3, cc = u & 7;                                                \
      async16((STRIPSRC) + s * 128 + ((cc ^ (s & 7)) << 4),                      \
              smem + (it * 256 + (tid & ~63)) * 16);                             \
    }                                                                            \
  }                                                                              \
  __syncthreads();

#define CONV_KLOOP3(WQ)                                                          \
  _Pragma("unroll")                                                              \
  for (int kk = 0; kk < 9; ++kk) {                                               \
    const int dkk = (kk / 3) * 58 + (kk % 3);                                    \
    int aaddr[7];                                                                \
    _Pragma("unroll")                                                            \
    for (int mi = 0; mi < 7; ++mi) {                                             \
      int s = sbase[mi] + dkk;                                                   \
      aaddr[mi] = (s << 7) + ((quad << 4) ^ ((s & 7) << 4));                     \
    }                                                                            \
    _Pragma("unroll")                                                            \
    for (int j = 0; j < 2; ++j) {                                                \
      i32x4 bf[4], af[7];                                                        \
      _Pragma("unroll")                                                          \
      for (int ni = 0; ni < 4; ++ni)                                             \
        bf[ni] = *(const i32x4*)((WQ) + kk * 16384 + bgoff[ni] + (j << 6));      \
      _Pragma("unroll")                                                          \
      for (int mi = 0; mi < 7; ++mi)                                             \
        af[mi] = *(const i32x4*)(smem + (aaddr[mi] ^ (j << 6)));                 \
      __builtin_amdgcn_s_setprio(1);                                             \
      _Pragma("unroll")                                                          \
      for (int mi = 0; mi < 7; ++mi)                                             \
        _Pragma("unroll")                                                        \
        for (int ni = 0; ni < 4; ++ni)                                           \
          acc[mi][ni] = __builtin_amdgcn_mfma_i32_16x16x64_i8(af[mi], bf[ni], acc[mi][ni], 0, 0, 0); \
      __builtin_amdgcn_s_setprio(0);                                             \
    }                                                                            \
  }

// ---------------- conv pass: q?p -> y i16 + stats (used for both convs) ----------------
// y target selectable per image: n < nsplit -> ylo[n], else yhi[n-nsplit]
__global__ __launch_bounds__(256, 2)
void k_conv(const unsigned char* __restrict__ act, const unsigned char* __restrict__ wq,
            short* __restrict__ ylo, short* __restrict__ yhi, int nsplit,
            float* __restrict__ stats) {
  __shared__ __align__(16) char smem[SMEMC];   // 44.5K strip + 1K red
  const int bidx = ((blockIdx.x & 7) * 112) + (blockIdx.x >> 3);  // XCD swizzle (896=8*112)
  const int n = bidx / 14, br = bidx % 14;
  const unsigned char* strip = act + (size_t)n * PADB + (size_t)br * 4 * PADW * 128;
  CONV_SETUP2
  CONV_STAGE_PRO(strip)
  CONV_KLOOP3(wq)
  short* yb = (n < nsplit ? ylo + (size_t)n * HWSZ * CH
                          : yhi + (size_t)(n - nsplit) * HWSZ * CH);
  const int pbase = br * BPIX;
  float lsum[4] = {0.f, 0.f, 0.f, 0.f}, lsq[4] = {0.f, 0.f, 0.f, 0.f};
#pragma unroll
  for (int mi = 0; mi < 7; ++mi) {
    int prow = pbase + m_base + mi * 16 + quad * 4;
#pragma unroll
    for (int ni = 0; ni < 4; ++ni) {
      int co = n_base + ni * 16 + lrow;
#pragma unroll
      for (int rg = 0; rg < 4; ++rg) {
        float v = (float)acc[mi][ni][rg];  // D: col=lane&15, row=quad*4+rg
        yb[(size_t)(prow + rg) * CH + co] = (short)fminf(fmaxf(v, -32767.f), 32767.f);
        lsum[ni] += v; lsq[ni] += v * v;
      }
    }
  }
#pragma unroll
  for (int ni = 0; ni < 4; ++ni) {
    lsum[ni] += __shfl_xor(lsum[ni], 16); lsum[ni] += __shfl_xor(lsum[ni], 32);
    lsq[ni]  += __shfl_xor(lsq[ni], 16);  lsq[ni]  += __shfl_xor(lsq[ni], 32);
  }
  __syncthreads();
  float* red = (float*)(smem + REDOFF);
  red[tid] = 0.f;
  __syncthreads();
  if (quad == 0) {
#pragma unroll
    for (int ni = 0; ni < 4; ++ni) {
      int co = n_base + ni * 16 + lrow;
      atomicAdd(&red[co], lsum[ni]);
      atomicAdd(&red[CH + co], lsq[ni]);
    }
  }
  __syncthreads();
  atomicAdd(&stats[tid], red[tid]);
}

// ---------------- BN1(inline) + act quant: y i16 -> q2p int8 padded (+halo zero) ----------------
// v2: 16 elems/thread (32 B loads, 16 B stores)
__global__ void k_bnq(const short* __restrict__ y, const float* __restrict__ stats,
                      const unsigned* __restrict__ abits, const float* __restrict__ g,
                      const float* __restrict__ b, unsigned char* __restrict__ q) {
  __shared__ float bnpS[256];
  int tid = threadIdx.x;
  bn_inline(tid, stats, abits, g, b, bnpS);
  if (blockIdx.x < 64) halo_zero(q + (size_t)blockIdx.x * PADB, tid);
  __syncthreads();
  size_t i = (size_t)blockIdx.x * 256 + tid;           // 16 elems/thread
  short8 v0 = ((const short8*)y)[i * 2];
  short8 v1 = ((const short8*)y)[i * 2 + 1];
  int c0 = (int)((i * 16) & (CH - 1));
  int pix = (int)(i >> 3);
  int n = pix / HWSZ, l = pix - n * HWSZ;
  int h = l / IMG, w = l - h * IMG;
  unsigned u[4] = {0u, 0u, 0u, 0u};
#pragma unroll
  for (int j = 0; j < 8; ++j) {
    float a0 = (float)v0[j] * bnpS[c0 + j] + bnpS[CH + c0 + j];
    float a1 = (float)v1[j] * bnpS[c0 + 8 + j] + bnpS[CH + c0 + 8 + j];
    unsigned q0 = (unsigned)(int)rintf(fminf(fmaxf(a0, 0.f), 1.f) * 15.f);
    unsigned q1 = (unsigned)(int)rintf(fminf(fmaxf(a1, 0.f), 1.f) * 15.f);
    u[j >> 2]       |= q0 << (8 * (j & 3));
    u[2 + (j >> 2)] |= q1 << (8 * (j & 3));
  }
  *(uint4*)(q + (size_t)n * PADB + ((h + 1) * PADW + (w + 1)) * 128 + c0) =
      (uint4){u[0], u[1], u[2], u[3]};
}

// ---------------- finale v2: BN2 + residual, wide y2 loads, full-channel tile ----------------
__global__ void k_fin(const short* __restrict__ ylo, const short* __restrict__ yhi, int nsplit,
                      const float* __restrict__ stats,
                      const unsigned* __restrict__ abits, const float* __restrict__ g,
                      const float* __restrict__ b, const float* __restrict__ x,
                      float* __restrict__ out, int img0) {
  __shared__ float bnpS[256];
  __shared__ float tile[128][33];
  int tx = threadIdx.x, ty = threadIdx.y, lin = ty * 32 + tx;
  bn_inline(lin, stats, abits, g, b, bnpS);
  __syncthreads();
  int n = img0 + blockIdx.z, p0 = blockIdx.x * 32;
  int p = lin >> 3, c0 = (lin & 7) * 16;
  const short* ybase = (n < nsplit ? ylo + (size_t)n * HWSZ * CH
                                   : yhi + (size_t)(n - nsplit) * HWSZ * CH);
  const short* ys = ybase + (size_t)(p0 + p) * CH + c0;   // 32 B/lane, 256 B/pixel
  short8 v0 = *(const short8*)ys;
  short8 v1 = *(const short8*)(ys + 8);
#pragma unroll
  for (int j = 0; j < 8; ++j) {
    tile[c0 + j][p]     = (float)v0[j] * bnpS[c0 + j]     + bnpS[CH + c0 + j];
    tile[c0 + 8 + j][p] = (float)v1[j] * bnpS[c0 + 8 + j] + bnpS[CH + c0 + 8 + j];
  }
  __syncthreads();
  const float* xs = x + (size_t)n * CH * HWSZ;
  float*       os = out + (size_t)n * CH * HWSZ;
#pragma unroll
  for (int r = 0; r < 16; ++r) {
    int c = ty + r * 8;
    size_t a = (size_t)c * HWSZ + p0 + tx;
    os[a] = tile[c][tx] + xs[a];                       // coalesced along p
  }
}

// ---------------- Plan B only: recompute conv2 for image 63 + BN2 + residual ----------------
__global__ __launch_bounds__(256, 2)
void k_conv_out63(const unsigned char* __restrict__ act, const unsigned char* __restrict__ wq,
                  const float* __restrict__ stats, const unsigned* __restrict__ abits,
                  const float* __restrict__ g, const float* __restrict__ b,
                  const float* __restrict__ x, float* __restrict__ out) {
  __shared__ __align__(16) char smem[SMEM63];
  __shared__ float bnpS[256];
  bn_inline(threadIdx.x, stats, abits, g, b, bnpS);
  const int br = blockIdx.x;          // 0..13, one image (63)
  const unsigned char* strip = act + (size_t)br * 4 * PADW * 128;
  CONV_SETUP2
  CONV_STAGE_PRO(strip)
  CONV_KLOOP3(wq)
  __syncthreads();
  f16 (*tile)[228] = (f16(*)[228])smem;     // repurpose strip area (128*228*2 = 58368 B)
#pragma unroll
  for (int ni = 0; ni < 4; ++ni) {
    int co = n_base + ni * 16 + lrow;
    float sc = bnpS[co], sh = bnpS[CH + co];
#pragma unroll
    for (int mi = 0; mi < 7; ++mi) {
      int pr = m_base + mi * 16 + quad * 4;
#pragma unroll
      for (int rg = 0; rg < 4; ++rg)
        tile[co][pr + rg] = (f16)((float)acc[mi][ni][rg] * sc + sh);
    }
  }
  __syncthreads();
  int c = tid >> 1, seg = tid & 1;
  int pl0 = br * BPIX + seg * 112;
  size_t gb = ((size_t)63 * CH + c) * HWSZ + pl0;
  const float* xp = x + gb;
  float* op = out + gb;
  const f16* tr = &tile[c][seg * 112];
#pragma unroll
  for (int j = 0; j < 112; j += 4) {
    f32x4 xv = *(const f32x4*)(xp + j);
    f32x4 ov;
    ov[0] = (float)tr[j]     + xv[0];
    ov[1] = (float)tr[j + 1] + xv[1];
    ov[2] = (float)tr[j + 2] + xv[2];
    ov[3] = (float)tr[j + 3] + xv[3];
    *(f32x4*)(op + j) = ov;
  }
}

extern "C" void kernel_launch(void* const* d_in, const int* in_sizes, int n_in,
                              void* d_out, int out_size, void* d_ws, size_t ws_size,
                              hipStream_t stream) {
  (void)in_sizes; (void)n_in; (void)out_size;
  const float* x  = (const float*)d_in[0];
  const float* w1 = (const float*)d_in[1];
  const float* w2 = (const float*)d_in[2];
  const float* g1 = (const float*)d_in[3];
  const float* b1 = (const float*)d_in[4];
  const float* g2 = (const float*)d_in[5];
  const float* b2 = (const float*)d_in[6];
  float* out = (float*)d_out;

  char* dob = (char*)d_out;
  unsigned char* q1p = (unsigned char*)dob;            // padded i8 [0, 27.56M)
  unsigned char* q2p = (unsigned char*)dob;            // same region (q1p dead by then)
  short* y1 = (short*)(dob + YOFF);                    // i16 NHWC [27.56M, 78.94M)

  char* ws = (char*)d_ws;
  unsigned* alpha_bits = (unsigned*)ws;
  float* stats1 = (float*)(ws + 256);
  float* stats2 = (float*)(ws + 1280);

  hipMemsetAsync(ws, 0, 4608, stream);                 // alpha + stats
  k_wmax  <<<64, 256, 0, stream>>>(w1, w2, alpha_bits);

  if (ws_size >= 51679744u) {
    // ---- Plan A: everything conflict-free in ws ----
    unsigned char* wq1 = (unsigned char*)(ws + 4608);
    unsigned char* wq2 = (unsigned char*)(ws + 152064);
    short* y2 = (short*)(ws + 299520);
    k_wquant<<<2 * WELEMS / 256, 256, 0, stream>>>(w1, w2, alpha_bits, wq1, wq2);
    k_actq  <<<dim3(98, 1, 64), dim3(32, 8), 0, stream>>>(x, q1p);
    k_conv  <<<NBLK, 256, 0, stream>>>(q1p, wq1, y1, y1, 64, stats1);
    k_bnq   <<<NPIX * CH / 4096, 256, 0, stream>>>(y1, stats1, alpha_bits + 0, g1, b1, q2p);
    k_conv  <<<NBLK, 256, 0, stream>>>(q2p, wq2, y2, y2, 64, stats2);
    k_fin   <<<dim3(98, 1, 64), dim3(32, 8), 0, stream>>>(y2, y2, 64, stats2, alpha_bits + 1, g2, b2, x, out, 0);
    return;
  }

  // ---- Plan B family: wq1 parked in d_out (dead after conv1), wq2 in ws ----
  unsigned char* wq1 = (unsigned char*)(dob + WQ1OFF_B);
  unsigned char* wq2 = (unsigned char*)(ws + 4608);
  short* y2lo = (short*)(dob + Y2OFF_B);
  k_wquant<<<2 * WELEMS / 256, 256, 0, stream>>>(w1, w2, alpha_bits, wq1, wq2);
  k_actq  <<<dim3(98, 1, 64), dim3(32, 8), 0, stream>>>(x, q1p);
  k_conv  <<<NBLK, 256, 0, stream>>>(q1p, wq1, y1, y1, 64, stats1);
  k_bnq   <<<NPIX * CH / 4096, 256, 0, stream>>>(y1, stats1, alpha_bits + 0, g1, b1, q2p);

  if (ws_size >= 152064u + 32u * IMGB) {
    // ---- Plan B2: y2 imgs 0..31 in d_out top, imgs 32..63 in ws -> 2-launch finale ----
    short* y2hi = (short*)(ws + 152064);
    k_conv <<<NBLK, 256, 0, stream>>>(q2p, wq2, y2lo, y2hi, 32, stats2);
    k_fin <<<dim3(98, 1, 32), dim3(32, 8), 0, stream>>>(y2lo, y2hi, 32, stats2, alpha_bits + 1, g2, b2, x, out, 0);
    k_fin <<<dim3(98, 1, 32), dim3(32, 8), 0, stream>>>(y2lo, y2hi, 32, stats2, alpha_bits + 1, g2, b2, x, out, 32);
  } else if (ws_size >= 152064u + 16u * IMGB) {
    // ---- Plan B3: y2 imgs 0..47 in d_out top, imgs 48..63 in ws -> 3-launch finale ----
    short* y2hi = (short*)(ws + 152064);
    k_conv <<<NBLK, 256, 0, stream>>>(q2p, wq2, y2lo, y2hi, 48, stats2);
    k_fin <<<dim3(98, 1, 32), dim3(32, 8), 0, stream>>>(y2lo, y2hi, 48, stats2, alpha_bits + 1, g2, b2, x, out, 0);
    k_fin <<<dim3(98, 1, 16), dim3(32, 8), 0, stream>>>(y2lo, y2hi, 48, stats2, alpha_bits + 1, g2, b2, x, out, 32);
    k_fin <<<dim3(98, 1, 16), dim3(32, 8), 0, stream>>>(y2lo, y2hi, 48, stats2, alpha_bits + 1, g2, b2, x, out, 48);
  } else {
    // ---- Plan B classic (proven ws budget 582,656 B) ----
    unsigned char* q63p = (unsigned char*)(ws + 152064); // 430,592 B
    k_conv <<<NBLK, 256, 0, stream>>>(q2p, wq2, y2lo, y2lo, 64, stats2);
    // in-place finale: out[n] destroys y2[2n-64, 2n-63]; batch [a,b] safe iff 2b+2 <= 64+a
    hipMemcpyAsync(q63p, q2p + (size_t)63 * PADB, PADB, hipMemcpyDeviceToDevice, stream);
    k_fin <<<dim3(98, 1, 32), dim3(32, 8), 0, stream>>>(y2lo, y2lo, 64, stats2, alpha_bits + 1, g2, b2, x, out, 0);
    k_fin <<<dim3(98, 1, 16), dim3(32, 8), 0, stream>>>(y2lo, y2lo, 64, stats2, alpha_bits + 1, g2, b2, x, out, 32);
    k_fin <<<dim3(98, 1,  8), dim3(32, 8), 0, stream>>>(y2lo, y2lo, 64, stats2, alpha_bits + 1, g2, b2, x, out, 48);
    k_fin <<<dim3(98, 1,  4), dim3(32, 8), 0, stream>>>(y2lo, y2lo, 64, stats2, alpha_bits + 1, g2, b2, x, out, 56);
    k_fin <<<dim3(98, 1,  2), dim3(32, 8), 0, stream>>>(y2lo, y2lo, 64, stats2, alpha_bits + 1, g2, b2, x, out, 60);
    k_fin <<<dim3(98, 1,  1), dim3(32, 8), 0, stream>>>(y2lo, y2lo, 64, stats2, alpha_bits + 1, g2, b2, x, out, 62);
    k_conv_out63<<<14, 256, 0, stream>>>(q63p, wq2, stats2, alpha_bits + 1, g2, b2, x, out);
  }
}

// Round 6
// 346.516 us; speedup vs baseline: 1.0292x; 1.0292x over previous
//
#include <hip/hip_runtime.h>

#define CH    128
#define IMG   56
#define PADW  58
#define HWSZ  3136
#define NPIX  200704        // 64*3136
#define WELEMS 147456       // 128*128*9
#define BNEPS 1e-5f
#define PADB  430592        // 58*58*128, one halo-padded i8 image
#define YOFF  27557888u     // y1 i16 NHWC in d_out
#define Y2OFF_B 51380224u   // Plan B: y2 in d_out top half
#define WQ1OFF_B 78938112u  // Plan B: wq1 parked above y1
#define IMGB  802816u       // one image of y (HWSZ*CH*2)

// conv-v5 geometry: 224 output pixels (4 image rows) per block, 4 waves
#define BPIX   224
#define NBLK   (NPIX / BPIX)        // 896
#define STRIPB 44544                // 6 padded rows * 58 * 128
#define STRIPC 2784                 // 16B chunks in strip
#define REDOFF 44544                // stats reduction scratch (after strip)
#define SMEMC  45568                // k_conv smem: strip + 1K red
#define SMEM63 58368                // out63 smem: strip + f16 tile[128][228]

typedef float f32x4 __attribute__((ext_vector_type(4)));
typedef int   i32x4 __attribute__((ext_vector_type(4)));
typedef short short8 __attribute__((ext_vector_type(8)));
typedef _Float16 f16;

__device__ __forceinline__ void async16(const void* g, void* l) {
  __builtin_amdgcn_global_load_lds(
      (const __attribute__((address_space(1))) unsigned int*)g,
      (__attribute__((address_space(3))) unsigned int*)l, 16, 0, 0);
}
// inline BN-param compute (per-block, channels 0..127 -> bnpS[0..255])
__device__ __forceinline__ void bn_inline(int lin, const float* stats, const unsigned* abits,
                                          const float* g, const float* b, float* bnpS) {
  if (lin < 128) {
    const float inv = 1.f / (float)NPIX;
    float gs   = (__uint_as_float(*abits) + 1e-12f) * (1.f / 105.f);
    float mean = stats[lin] * inv;
    float var  = fmaxf(stats[CH + lin] * inv - mean * mean, 0.f);
    float sc   = g[lin] * gs * rsqrtf(gs * gs * var + BNEPS);
    bnpS[lin]      = sc;
    bnpS[CH + lin] = b[lin] - sc * mean;
  }
}
// zero the 29,184-byte halo of one padded image (1824 16B chunks, 256 threads)
__device__ __forceinline__ void halo_zero(unsigned char* qb, int lin) {
  for (int i = lin; i < 1824; i += 256) {
    size_t off;
    if (i < 464)      off = (size_t)i * 16;                                  // row 0
    else if (i < 928) off = (size_t)57 * PADW * 128 + (size_t)(i - 464) * 16; // row 57
    else {
      int j = i - 928, loc = j >> 3, sub = j & 7;
      int row = 1 + (loc >> 1), col = (loc & 1) ? 57 : 0;
      off = ((size_t)row * PADW + col) * 128 + (size_t)sub * 16;
    }
    *(uint4*)(qb + off) = (uint4){0u, 0u, 0u, 0u};
  }
}

// ---------------- weight absmax ----------------
__global__ void k_wmax(const float* __restrict__ w1, const float* __restrict__ w2,
                       unsigned* __restrict__ alpha_bits) {
  int idx = blockIdx.x * 256 + threadIdx.x;
  float m1 = 0.f, m2 = 0.f;
  for (int i = idx; i < WELEMS; i += gridDim.x * 256) {
    m1 = fmaxf(m1, fabsf(w1[i]));
    m2 = fmaxf(m2, fabsf(w2[i]));
  }
#pragma unroll
  for (int off = 32; off > 0; off >>= 1) {
    m1 = fmaxf(m1, __shfl_xor(m1, off));
    m2 = fmaxf(m2, __shfl_xor(m2, off));
  }
  __shared__ float s1[4], s2[4];
  int wave = threadIdx.x >> 6;
  if ((threadIdx.x & 63) == 0) { s1[wave] = m1; s2[wave] = m2; }
  __syncthreads();
  if (threadIdx.x == 0) {
    m1 = fmaxf(fmaxf(s1[0], s1[1]), fmaxf(s1[2], s1[3]));
    m2 = fmaxf(fmaxf(s2[0], s2[1]), fmaxf(s2[2], s2[3]));
    atomicMax(&alpha_bits[0], __float_as_uint(m1));
    atomicMax(&alpha_bits[1], __float_as_uint(m2));
  }
}

// ---------------- weight quantize to int8 (-7..7), OIHW -> [kk][co][ci] ----------------
__global__ void k_wquant(const float* __restrict__ w1, const float* __restrict__ w2,
                         const unsigned* __restrict__ alpha_bits,
                         unsigned char* __restrict__ wq1, unsigned char* __restrict__ wq2) {
  int idx = blockIdx.x * 256 + threadIdx.x;
  int t = idx >= WELEMS;
  int j = t ? idx - WELEMS : idx;
  int kk  = j >> 14;
  int rem = j & 16383;
  int co = rem >> 7, ci = rem & 127;
  float alpha = __uint_as_float(alpha_bits[t]) + 1e-12f;
  float v  = (t ? w2 : w1)[co * 1152 + ci * 9 + kk];
  float wc = fminf(fmaxf(v / alpha, -1.f), 1.f);
  int q = (int)rintf(wc * 7.f);
  (t ? wq2 : wq1)[j] = (unsigned char)(q & 0xFF);   // two's-complement int8
}

// ---------------- act quant v2: full-channel tile, wide NHWC stores ----------------
__global__ void k_actq(const float* __restrict__ x, unsigned char* __restrict__ qx) {
  __shared__ float tile[128][33];
  int n = blockIdx.z, p0 = blockIdx.x * 32;
  int tx = threadIdx.x, ty = threadIdx.y, lin = ty * 32 + tx;
  unsigned char* qb = qx + (size_t)n * PADB;
  if (blockIdx.x == 0) halo_zero(qb, lin);
  const float* xs = x + (size_t)n * CH * HWSZ;
#pragma unroll
  for (int r = 0; r < 16; ++r) {
    int c = ty + r * 8;
    float v = xs[(size_t)c * HWSZ + p0 + tx];       // coalesced along p
    v = fminf(fmaxf(v, 0.f), 1.f);                  // kills NaN too
    tile[c][tx] = rintf(v * 15.f);
  }
  __syncthreads();
  int p = lin >> 3, q8 = lin & 7;
  int pl = p0 + p;
  int h = pl / IMG, w = pl - h * IMG;
  unsigned u[4];
#pragma unroll
  for (int k = 0; k < 4; ++k) {
    unsigned b0 = (unsigned)(int)tile[q8 * 16 + k * 4 + 0][p];
    unsigned b1 = (unsigned)(int)tile[q8 * 16 + k * 4 + 1][p];
    unsigned b2 = (unsigned)(int)tile[q8 * 16 + k * 4 + 2][p];
    unsigned b3 = (unsigned)(int)tile[q8 * 16 + k * 4 + 3][p];
    u[k] = b0 | (b1 << 8) | (b2 << 16) | (b3 << 24);
  }
  *(uint4*)(qb + ((size_t)(h + 1) * PADW + (w + 1)) * 128 + q8 * 16) =
      (uint4){u[0], u[1], u[2], u[3]};
}

// ============ conv core v5: strip-resident A in LDS, B L2->VGPR with kk-level
// register double-buffer (software pipeline), ZERO K-loop barriers ============
// Round-5 lesson: unpipelined global->reg B loads expose ~250cy L2 latency per
// j-phase (MfmaUtil 17%). Fix: preload kk=0's B-frags; at top of kk issue the 8
// loads for kk+1 into bn*; compute kk from bc*; rotate bc<-bn (SSA-renamed away
// under full unroll). The in-flight loads span a whole kk's 56 MFMAs -> counted
// vmcnt, latency fully covered. +32 VGPR, still within the 2-wave/SIMD budget.
#define CONV_SETUP2                                                              \
  const int tid  = threadIdx.x;                                                  \
  const int lane = tid & 63;                                                     \
  const int quad = lane >> 4, lrow = lane & 15;                                  \
  const int m_base = ((tid >> 6) >> 1) * 112, n_base = ((tid >> 6) & 1) * 64;    \
  int sbase[7];                                                                  \
  _Pragma("unroll")                                                              \
  for (int mi = 0; mi < 7; ++mi) {                                               \
    int row = m_base + mi * 16 + lrow;                                           \
    sbase[mi] = (row / 56) * 58 + (row % 56);                                    \
  }                                                                              \
  int bgoff[4];                                                                  \
  _Pragma("unroll")                                                              \
  for (int ni = 0; ni < 4; ++ni)                                                 \
    bgoff[ni] = (n_base + ni * 16 + lrow) * 128 + (quad << 4);                   \
  i32x4 acc[7][4];                                                               \
  _Pragma("unroll")                                                              \
  for (int mi = 0; mi < 7; ++mi)                                                 \
    _Pragma("unroll")                                                            \
    for (int ni = 0; ni < 4; ++ni) acc[mi][ni] = (i32x4){0, 0, 0, 0};

// prologue: stage halo strip (linear LDS dest, inverse-swizzled source), ONE barrier
#define CONV_STAGE_PRO(STRIPSRC)                                                 \
  _Pragma("unroll")                                                              \
  for (int it = 0; it < 11; ++it) {                                              \
    int u = it * 256 + tid;                                                      \
    if (u < STRIPC) {                                                            \
      int s = u >> 3, cc = u & 7;                                                \
      async16((STRIPSRC) + s * 128 + ((cc ^ (s & 7)) << 4),                      \
              smem + (it * 256 + (tid & ~63)) * 16);                             \
    }                                                                            \
  }                                                                              \
  __syncthreads();

#define CONV_KLOOP4(WQ)                                                          \
  i32x4 bc0[4], bc1[4], bn0[4], bn1[4];                                          \
  _Pragma("unroll")                                                              \
  for (int ni = 0; ni < 4; ++ni) {                                               \
    bc0[ni] = *(const i32x4*)((WQ) + bgoff[ni]);                                 \
    bc1[ni] = *(const i32x4*)((WQ) + bgoff[ni] + 64);                            \
  }                                                                              \
  _Pragma("unroll")                                                              \
  for (int kk = 0; kk < 9; ++kk) {                                               \
    if (kk < 8) {                      /* issue kk+1's B loads NOW */            \
      _Pragma("unroll")                                                          \
      for (int ni = 0; ni < 4; ++ni) {                                           \
        bn0[ni] = *(const i32x4*)((WQ) + (kk + 1) * 16384 + bgoff[ni]);          \
        bn1[ni] = *(const i32x4*)((WQ) + (kk + 1) * 16384 + bgoff[ni] + 64);     \
      }                                                                          \
    }                                                                            \
    const int dkk = (kk / 3) * 58 + (kk % 3);                                    \
    int aaddr[7];                                                                \
    _Pragma("unroll")                                                            \
    for (int mi = 0; mi < 7; ++mi) {                                             \
      int s = sbase[mi] + dkk;                                                   \
      aaddr[mi] = (s << 7) + ((quad << 4) ^ ((s & 7) << 4));                     \
    }                                                                            \
    {                                  /* j = 0 : compute with bc0 */            \
      i32x4 af[7];                                                               \
      _Pragma("unroll")                                                          \
      for (int mi = 0; mi < 7; ++mi)                                             \
        af[mi] = *(const i32x4*)(smem + aaddr[mi]);                              \
      __builtin_amdgcn_s_setprio(1);                                             \
      _Pragma("unroll")                                                          \
      for (int mi = 0; mi < 7; ++mi)                                             \
        _Pragma("unroll")                                                        \
        for (int ni = 0; ni < 4; ++ni)                                           \
          acc[mi][ni] = __builtin_amdgcn_mfma_i32_16x16x64_i8(af[mi], bc0[ni], acc[mi][ni], 0, 0, 0); \
      __builtin_amdgcn_s_setprio(0);                                             \
    }                                                                            \
    {                                  /* j = 1 : compute with bc1 */            \
      i32x4 af[7];                                                               \
      _Pragma("unroll")                                                          \
      for (int mi = 0; mi < 7; ++mi)                                             \
        af[mi] = *(const i32x4*)(smem + (aaddr[mi] ^ 64));                       \
      __builtin_amdgcn_s_setprio(1);                                             \
      _Pragma("unroll")                                                          \
      for (int mi = 0; mi < 7; ++mi)                                             \
        _Pragma("unroll")                                                        \
        for (int ni = 0; ni < 4; ++ni)                                           \
          acc[mi][ni] = __builtin_amdgcn_mfma_i32_16x16x64_i8(af[mi], bc1[ni], acc[mi][ni], 0, 0, 0); \
      __builtin_amdgcn_s_setprio(0);                                             \
    }                                                                            \
    if (kk < 8) {                      /* rotate (renamed away after unroll) */  \
      _Pragma("unroll")                                                          \
      for (int ni = 0; ni < 4; ++ni) { bc0[ni] = bn0[ni]; bc1[ni] = bn1[ni]; }   \
    }                                                                            \
  }

// ---------------- conv pass: q?p -> y i16 + stats (used for both convs) ----------------
// y target selectable per image: n < nsplit -> ylo[n], else yhi[n-nsplit]
__global__ __launch_bounds__(256, 2)
void k_conv(const unsigned char* __restrict__ act, const unsigned char* __restrict__ wq,
            short* __restrict__ ylo, short* __restrict__ yhi, int nsplit,
            float* __restrict__ stats) {
  __shared__ __align__(16) char smem[SMEMC];   // 44.5K strip + 1K red
  const int bidx = ((blockIdx.x & 7) * 112) + (blockIdx.x >> 3);  // XCD swizzle (896=8*112)
  const int n = bidx / 14, br = bidx % 14;
  const unsigned char* strip = act + (size_t)n * PADB + (size_t)br * 4 * PADW * 128;
  CONV_SETUP2
  CONV_STAGE_PRO(strip)
  CONV_KLOOP4(wq)
  short* yb = (n < nsplit ? ylo + (size_t)n * HWSZ * CH
                          : yhi + (size_t)(n - nsplit) * HWSZ * CH);
  const int pbase = br * BPIX;
  float lsum[4] = {0.f, 0.f, 0.f, 0.f}, lsq[4] = {0.f, 0.f, 0.f, 0.f};
#pragma unroll
  for (int mi = 0; mi < 7; ++mi) {
    int prow = pbase + m_base + mi * 16 + quad * 4;
#pragma unroll
    for (int ni = 0; ni < 4; ++ni) {
      int co = n_base + ni * 16 + lrow;
#pragma unroll
      for (int rg = 0; rg < 4; ++rg) {
        float v = (float)acc[mi][ni][rg];  // D: col=lane&15, row=quad*4+rg
        yb[(size_t)(prow + rg) * CH + co] = (short)fminf(fmaxf(v, -32767.f), 32767.f);
        lsum[ni] += v; lsq[ni] += v * v;
      }
    }
  }
#pragma unroll
  for (int ni = 0; ni < 4; ++ni) {
    lsum[ni] += __shfl_xor(lsum[ni], 16); lsum[ni] += __shfl_xor(lsum[ni], 32);
    lsq[ni]  += __shfl_xor(lsq[ni], 16);  lsq[ni]  += __shfl_xor(lsq[ni], 32);
  }
  __syncthreads();
  float* red = (float*)(smem + REDOFF);
  red[tid] = 0.f;
  __syncthreads();
  if (quad == 0) {
#pragma unroll
    for (int ni = 0; ni < 4; ++ni) {
      int co = n_base + ni * 16 + lrow;
      atomicAdd(&red[co], lsum[ni]);
      atomicAdd(&red[CH + co], lsq[ni]);
    }
  }
  __syncthreads();
  atomicAdd(&stats[tid], red[tid]);
}

// ---------------- BN1(inline) + act quant: y i16 -> q2p int8 padded (+halo zero) ----------------
// v2: 16 elems/thread (32 B loads, 16 B stores)
__global__ void k_bnq(const short* __restrict__ y, const float* __restrict__ stats,
                      const unsigned* __restrict__ abits, const float* __restrict__ g,
                      const float* __restrict__ b, unsigned char* __restrict__ q) {
  __shared__ float bnpS[256];
  int tid = threadIdx.x;
  bn_inline(tid, stats, abits, g, b, bnpS);
  if (blockIdx.x < 64) halo_zero(q + (size_t)blockIdx.x * PADB, tid);
  __syncthreads();
  size_t i = (size_t)blockIdx.x * 256 + tid;           // 16 elems/thread
  short8 v0 = ((const short8*)y)[i * 2];
  short8 v1 = ((const short8*)y)[i * 2 + 1];
  int c0 = (int)((i * 16) & (CH - 1));
  int pix = (int)(i >> 3);
  int n = pix / HWSZ, l = pix - n * HWSZ;
  int h = l / IMG, w = l - h * IMG;
  unsigned u[4] = {0u, 0u, 0u, 0u};
#pragma unroll
  for (int j = 0; j < 8; ++j) {
    float a0 = (float)v0[j] * bnpS[c0 + j] + bnpS[CH + c0 + j];
    float a1 = (float)v1[j] * bnpS[c0 + 8 + j] + bnpS[CH + c0 + 8 + j];
    unsigned q0 = (unsigned)(int)rintf(fminf(fmaxf(a0, 0.f), 1.f) * 15.f);
    unsigned q1 = (unsigned)(int)rintf(fminf(fmaxf(a1, 0.f), 1.f) * 15.f);
    u[j >> 2]       |= q0 << (8 * (j & 3));
    u[2 + (j >> 2)] |= q1 << (8 * (j & 3));
  }
  *(uint4*)(q + (size_t)n * PADB + ((h + 1) * PADW + (w + 1)) * 128 + c0) =
      (uint4){u[0], u[1], u[2], u[3]};
}

// ---------------- finale v2: BN2 + residual, wide y2 loads, full-channel tile ----------------
__global__ void k_fin(const short* __restrict__ ylo, const short* __restrict__ yhi, int nsplit,
                      const float* __restrict__ stats,
                      const unsigned* __restrict__ abits, const float* __restrict__ g,
                      const float* __restrict__ b, const float* __restrict__ x,
                      float* __restrict__ out, int img0) {
  __shared__ float bnpS[256];
  __shared__ float tile[128][33];
  int tx = threadIdx.x, ty = threadIdx.y, lin = ty * 32 + tx;
  bn_inline(lin, stats, abits, g, b, bnpS);
  __syncthreads();
  int n = img0 + blockIdx.z, p0 = blockIdx.x * 32;
  int p = lin >> 3, c0 = (lin & 7) * 16;
  const short* ybase = (n < nsplit ? ylo + (size_t)n * HWSZ * CH
                                   : yhi + (size_t)(n - nsplit) * HWSZ * CH);
  const short* ys = ybase + (size_t)(p0 + p) * CH + c0;   // 32 B/lane, 256 B/pixel
  short8 v0 = *(const short8*)ys;
  short8 v1 = *(const short8*)(ys + 8);
#pragma unroll
  for (int j = 0; j < 8; ++j) {
    tile[c0 + j][p]     = (float)v0[j] * bnpS[c0 + j]     + bnpS[CH + c0 + j];
    tile[c0 + 8 + j][p] = (float)v1[j] * bnpS[c0 + 8 + j] + bnpS[CH + c0 + 8 + j];
  }
  __syncthreads();
  const float* xs = x + (size_t)n * CH * HWSZ;
  float*       os = out + (size_t)n * CH * HWSZ;
#pragma unroll
  for (int r = 0; r < 16; ++r) {
    int c = ty + r * 8;
    size_t a = (size_t)c * HWSZ + p0 + tx;
    os[a] = tile[c][tx] + xs[a];                       // coalesced along p
  }
}

// ---------------- Plan B only: recompute conv2 for image 63 + BN2 + residual ----------------
__global__ __launch_bounds__(256, 2)
void k_conv_out63(const unsigned char* __restrict__ act, const unsigned char* __restrict__ wq,
                  const float* __restrict__ stats, const unsigned* __restrict__ abits,
                  const float* __restrict__ g, const float* __restrict__ b,
                  const float* __restrict__ x, float* __restrict__ out) {
  __shared__ __align__(16) char smem[SMEM63];
  __shared__ float bnpS[256];
  bn_inline(threadIdx.x, stats, abits, g, b, bnpS);
  const int br = blockIdx.x;          // 0..13, one image (63)
  const unsigned char* strip = act + (size_t)br * 4 * PADW * 128;
  CONV_SETUP2
  CONV_STAGE_PRO(strip)
  CONV_KLOOP4(wq)
  __syncthreads();
  f16 (*tile)[228] = (f16(*)[228])smem;     // repurpose strip area (128*228*2 = 58368 B)
#pragma unroll
  for (int ni = 0; ni < 4; ++ni) {
    int co = n_base + ni * 16 + lrow;
    float sc = bnpS[co], sh = bnpS[CH + co];
#pragma unroll
    for (int mi = 0; mi < 7; ++mi) {
      int pr = m_base + mi * 16 + quad * 4;
#pragma unroll
      for (int rg = 0; rg < 4; ++rg)
        tile[co][pr + rg] = (f16)((float)acc[mi][ni][rg] * sc + sh);
    }
  }
  __syncthreads();
  int c = tid >> 1, seg = tid & 1;
  int pl0 = br * BPIX + seg * 112;
  size_t gb = ((size_t)63 * CH + c) * HWSZ + pl0;
  const float* xp = x + gb;
  float* op = out + gb;
  const f16* tr = &tile[c][seg * 112];
#pragma unroll
  for (int j = 0; j < 112; j += 4) {
    f32x4 xv = *(const f32x4*)(xp + j);
    f32x4 ov;
    ov[0] = (float)tr[j]     + xv[0];
    ov[1] = (float)tr[j + 1] + xv[1];
    ov[2] = (float)tr[j + 2] + xv[2];
    ov[3] = (float)tr[j + 3] + xv[3];
    *(f32x4*)(op + j) = ov;
  }
}

extern "C" void kernel_launch(void* const* d_in, const int* in_sizes, int n_in,
                              void* d_out, int out_size, void* d_ws, size_t ws_size,
                              hipStream_t stream) {
  (void)in_sizes; (void)n_in; (void)out_size;
  const float* x  = (const float*)d_in[0];
  const float* w1 = (const float*)d_in[1];
  const float* w2 = (const float*)d_in[2];
  const float* g1 = (const float*)d_in[3];
  const float* b1 = (const float*)d_in[4];
  const float* g2 = (const float*)d_in[5];
  const float* b2 = (const float*)d_in[6];
  float* out = (float*)d_out;

  char* dob = (char*)d_out;
  unsigned char* q1p = (unsigned char*)dob;            // padded i8 [0, 27.56M)
  unsigned char* q2p = (unsigned char*)dob;            // same region (q1p dead by then)
  short* y1 = (short*)(dob + YOFF);                    // i16 NHWC [27.56M, 78.94M)

  char* ws = (char*)d_ws;
  unsigned* alpha_bits = (unsigned*)ws;
  float* stats1 = (float*)(ws + 256);
  float* stats2 = (float*)(ws + 1280);

  hipMemsetAsync(ws, 0, 4608, stream);                 // alpha + stats
  k_wmax  <<<64, 256, 0, stream>>>(w1, w2, alpha_bits);

  if (ws_size >= 51679744u) {
    // ---- Plan A: everything conflict-free in ws ----
    unsigned char* wq1 = (unsigned char*)(ws + 4608);
    unsigned char* wq2 = (unsigned char*)(ws + 152064);
    short* y2 = (short*)(ws + 299520);
    k_wquant<<<2 * WELEMS / 256, 256, 0, stream>>>(w1, w2, alpha_bits, wq1, wq2);
    k_actq  <<<dim3(98, 1, 64), dim3(32, 8), 0, stream>>>(x, q1p);
    k_conv  <<<NBLK, 256, 0, stream>>>(q1p, wq1, y1, y1, 64, stats1);
    k_bnq   <<<NPIX * CH / 4096, 256, 0, stream>>>(y1, stats1, alpha_bits + 0, g1, b1, q2p);
    k_conv  <<<NBLK, 256, 0, stream>>>(q2p, wq2, y2, y2, 64, stats2);
    k_fin   <<<dim3(98, 1, 64), dim3(32, 8), 0, stream>>>(y2, y2, 64, stats2, alpha_bits + 1, g2, b2, x, out, 0);
    return;
  }

  // ---- Plan B family: wq1 parked in d_out (dead after conv1), wq2 in ws ----
  unsigned char* wq1 = (unsigned char*)(dob + WQ1OFF_B);
  unsigned char* wq2 = (unsigned char*)(ws + 4608);
  short* y2lo = (short*)(dob + Y2OFF_B);
  k_wquant<<<2 * WELEMS / 256, 256, 0, stream>>>(w1, w2, alpha_bits, wq1, wq2);
  k_actq  <<<dim3(98, 1, 64), dim3(32, 8), 0, stream>>>(x, q1p);
  k_conv  <<<NBLK, 256, 0, stream>>>(q1p, wq1, y1, y1, 64, stats1);
  k_bnq   <<<NPIX * CH / 4096, 256, 0, stream>>>(y1, stats1, alpha_bits + 0, g1, b1, q2p);

  if (ws_size >= 152064u + 32u * IMGB) {
    // ---- Plan B2: y2 imgs 0..31 in d_out top, imgs 32..63 in ws -> 2-launch finale ----
    short* y2hi = (short*)(ws + 152064);
    k_conv <<<NBLK, 256, 0, stream>>>(q2p, wq2, y2lo, y2hi, 32, stats2);
    k_fin <<<dim3(98, 1, 32), dim3(32, 8), 0, stream>>>(y2lo, y2hi, 32, stats2, alpha_bits + 1, g2, b2, x, out, 0);
    k_fin <<<dim3(98, 1, 32), dim3(32, 8), 0, stream>>>(y2lo, y2hi, 32, stats2, alpha_bits + 1, g2, b2, x, out, 32);
  } else if (ws_size >= 152064u + 16u * IMGB) {
    // ---- Plan B3: y2 imgs 0..47 in d_out top, imgs 48..63 in ws -> 3-launch finale ----
    short* y2hi = (short*)(ws + 152064);
    k_conv <<<NBLK, 256, 0, stream>>>(q2p, wq2, y2lo, y2hi, 48, stats2);
    k_fin <<<dim3(98, 1, 32), dim3(32, 8), 0, stream>>>(y2lo, y2hi, 48, stats2, alpha_bits + 1, g2, b2, x, out, 0);
    k_fin <<<dim3(98, 1, 16), dim3(32, 8), 0, stream>>>(y2lo, y2hi, 48, stats2, alpha_bits + 1, g2, b2, x, out, 32);
    k_fin <<<dim3(98, 1, 16), dim3(32, 8), 0, stream>>>(y2lo, y2hi, 48, stats2, alpha_bits + 1, g2, b2, x, out, 48);
  } else {
    // ---- Plan B classic (proven ws budget 582,656 B) ----
    unsigned char* q63p = (unsigned char*)(ws + 152064); // 430,592 B
    k_conv <<<NBLK, 256, 0, stream>>>(q2p, wq2, y2lo, y2lo, 64, stats2);
    // in-place finale: out[n] destroys y2[2n-64, 2n-63]; batch [a,b] safe iff 2b+2 <= 64+a
    hipMemcpyAsync(q63p, q2p + (size_t)63 * PADB, PADB, hipMemcpyDeviceToDevice, stream);
    k_fin <<<dim3(98, 1, 32), dim3(32, 8), 0, stream>>>(y2lo, y2lo, 64, stats2, alpha_bits + 1, g2, b2, x, out, 0);
    k_fin <<<dim3(98, 1, 16), dim3(32, 8), 0, stream>>>(y2lo, y2lo, 64, stats2, alpha_bits + 1, g2, b2, x, out, 32);
    k_fin <<<dim3(98, 1,  8), dim3(32, 8), 0, stream>>>(y2lo, y2lo, 64, stats2, alpha_bits + 1, g2, b2, x, out, 48);
    k_fin <<<dim3(98, 1,  4), dim3(32, 8), 0, stream>>>(y2lo, y2lo, 64, stats2, alpha_bits + 1, g2, b2, x, out, 56);
    k_fin <<<dim3(98, 1,  2), dim3(32, 8), 0, stream>>>(y2lo, y2lo, 64, stats2, alpha_bits + 1, g2, b2, x, out, 60);
    k_fin <<<dim3(98, 1,  1), dim3(32, 8), 0, stream>>>(y2lo, y2lo, 64, stats2, alpha_bits + 1, g2, b2, x, out, 62);
    k_conv_out63<<<14, 256, 0, stream>>>(q63p, wq2, stats2, alpha_bits + 1, g2, b2, x, out);
  }
}

// Round 8
// 323.478 us; speedup vs baseline: 1.1025x; 1.0712x over previous
//
#include <hip/hip_runtime.h>

#define CH    128
#define IMG   56
#define PADW  58
#define HWSZ  3136
#define NPIX  200704        // 64*3136
#define WELEMS 147456       // 128*128*9
#define BNEPS 1e-5f
#define PADB  430592        // 58*58*128, one halo-padded i8 image
#define YOFF  27557888u     // y1 i16 NHWC in d_out
#define Y2OFF_B 51380224u   // Plan B: y2 in d_out top half
#define WQ1OFF_B 78938112u  // Plan B: wq1 parked above y1
#define IMGB  802816u       // one image of y (HWSZ*CH*2)

// conv-v3 geometry: 224 output pixels (4 image rows) per block
#define BPIX   224
#define NBLK   (NPIX / BPIX)        // 896
#define STRIPB 44544                // 6 padded rows * 58 * 128
#define STRIPC 2784                 // 16B chunks in strip
#define BBASE  44544                // B double-buffer base in smem
#define REDOFF 77312                // stats reduction scratch
#define SMEMSZ 78336

typedef float f32x4 __attribute__((ext_vector_type(4)));
typedef int   i32x4 __attribute__((ext_vector_type(4)));
typedef short short8 __attribute__((ext_vector_type(8)));
typedef _Float16 f16;

__device__ __forceinline__ void async16(const void* g, void* l) {
  __builtin_amdgcn_global_load_lds(
      (const __attribute__((address_space(1))) unsigned int*)g,
      (__attribute__((address_space(3))) unsigned int*)l, 16, 0, 0);
}
// inline BN-param compute (per-block, channels 0..127 -> bnpS[0..255])
__device__ __forceinline__ void bn_inline(int lin, const float* stats, const unsigned* abits,
                                          const float* g, const float* b, float* bnpS) {
  if (lin < 128) {
    const float inv = 1.f / (float)NPIX;
    float gs   = (__uint_as_float(*abits) + 1e-12f) * (1.f / 105.f);
    float mean = stats[lin] * inv;
    float var  = fmaxf(stats[CH + lin] * inv - mean * mean, 0.f);
    float sc   = g[lin] * gs * rsqrtf(gs * gs * var + BNEPS);
    bnpS[lin]      = sc;
    bnpS[CH + lin] = b[lin] - sc * mean;
  }
}
// zero the 29,184-byte halo of one padded image (1824 16B chunks, 256 threads)
__device__ __forceinline__ void halo_zero(unsigned char* qb, int lin) {
  for (int i = lin; i < 1824; i += 256) {
    size_t off;
    if (i < 464)      off = (size_t)i * 16;                                  // row 0
    else if (i < 928) off = (size_t)57 * PADW * 128 + (size_t)(i - 464) * 16; // row 57
    else {
      int j = i - 928, loc = j >> 3, sub = j & 7;
      int row = 1 + (loc >> 1), col = (loc & 1) ? 57 : 0;
      off = ((size_t)row * PADW + col) * 128 + (size_t)sub * 16;
    }
    *(uint4*)(qb + off) = (uint4){0u, 0u, 0u, 0u};
  }
}

// ---------------- weight absmax ----------------
__global__ void k_wmax(const float* __restrict__ w1, const float* __restrict__ w2,
                       unsigned* __restrict__ alpha_bits) {
  int idx = blockIdx.x * 256 + threadIdx.x;
  float m1 = 0.f, m2 = 0.f;
  for (int i = idx; i < WELEMS; i += gridDim.x * 256) {
    m1 = fmaxf(m1, fabsf(w1[i]));
    m2 = fmaxf(m2, fabsf(w2[i]));
  }
#pragma unroll
  for (int off = 32; off > 0; off >>= 1) {
    m1 = fmaxf(m1, __shfl_xor(m1, off));
    m2 = fmaxf(m2, __shfl_xor(m2, off));
  }
  __shared__ float s1[4], s2[4];
  int wave = threadIdx.x >> 6;
  if ((threadIdx.x & 63) == 0) { s1[wave] = m1; s2[wave] = m2; }
  __syncthreads();
  if (threadIdx.x == 0) {
    m1 = fmaxf(fmaxf(s1[0], s1[1]), fmaxf(s1[2], s1[3]));
    m2 = fmaxf(fmaxf(s2[0], s2[1]), fmaxf(s2[2], s2[3]));
    atomicMax(&alpha_bits[0], __float_as_uint(m1));
    atomicMax(&alpha_bits[1], __float_as_uint(m2));
  }
}

// ---------------- weight quantize to int8 (-7..7), OIHW -> [kk][co][ci] ----------------
__global__ void k_wquant(const float* __restrict__ w1, const float* __restrict__ w2,
                         const unsigned* __restrict__ alpha_bits,
                         unsigned char* __restrict__ wq1, unsigned char* __restrict__ wq2) {
  int idx = blockIdx.x * 256 + threadIdx.x;
  int t = idx >= WELEMS;
  int j = t ? idx - WELEMS : idx;
  int kk  = j >> 14;
  int rem = j & 16383;
  int co = rem >> 7, ci = rem & 127;
  float alpha = __uint_as_float(alpha_bits[t]) + 1e-12f;
  float v  = (t ? w2 : w1)[co * 1152 + ci * 9 + kk];
  float wc = fminf(fmaxf(v / alpha, -1.f), 1.f);
  int q = (int)rintf(wc * 7.f);
  (t ? wq2 : wq1)[j] = (unsigned char)(q & 0xFF);   // two's-complement int8
}

// ---------------- act quant v2: full-channel tile, wide NHWC stores ----------------
// 128c x 32p tile; load coalesced along p; store 16 B/lane (128 B contiguous/pixel).
__global__ void k_actq(const float* __restrict__ x, unsigned char* __restrict__ qx) {
  __shared__ float tile[128][33];
  int n = blockIdx.z, p0 = blockIdx.x * 32;
  int tx = threadIdx.x, ty = threadIdx.y, lin = ty * 32 + tx;
  unsigned char* qb = qx + (size_t)n * PADB;
  if (blockIdx.x == 0) halo_zero(qb, lin);
  const float* xs = x + (size_t)n * CH * HWSZ;
#pragma unroll
  for (int r = 0; r < 16; ++r) {
    int c = ty + r * 8;
    float v = xs[(size_t)c * HWSZ + p0 + tx];       // coalesced along p
    v = fminf(fmaxf(v, 0.f), 1.f);                  // kills NaN too
    tile[c][tx] = rintf(v * 15.f);
  }
  __syncthreads();
  int p = lin >> 3, q8 = lin & 7;
  int pl = p0 + p;
  int h = pl / IMG, w = pl - h * IMG;
  unsigned u[4];
#pragma unroll
  for (int k = 0; k < 4; ++k) {
    unsigned b0 = (unsigned)(int)tile[q8 * 16 + k * 4 + 0][p];
    unsigned b1 = (unsigned)(int)tile[q8 * 16 + k * 4 + 1][p];
    unsigned b2 = (unsigned)(int)tile[q8 * 16 + k * 4 + 2][p];
    unsigned b3 = (unsigned)(int)tile[q8 * 16 + k * 4 + 3][p];
    u[k] = b0 | (b1 << 8) | (b2 << 16) | (b3 << 24);
  }
  *(uint4*)(qb + ((size_t)(h + 1) * PADW + (w + 1)) * 128 + q8 * 16) =
      (uint4){u[0], u[1], u[2], u[3]};
}

// ============ conv core v3 (PROVEN BEST, round-4): strip-resident acts,
// weight-only per-kk LDS streaming, double-buffered, one barrier/kk ============
// r5 (B direct global->reg, no pipe): 63 us — L2 latency exposed.
// r6 (B global->reg + register dbuf): 77 us — compiler sinks the loads (VGPR 120
// not ~200), pipeline defeated at source level. This staged version: kk+1 B
// prefetch issued at top of kk via global_load_lds; barrier drain at end of kk
// has a full ~2300-cycle compute phase of cover. Best measured (total 325.6).
#define CONV_SETUP2                                                              \
  const int tid  = threadIdx.x;                                                  \
  const int lane = tid & 63;                                                     \
  const int quad = lane >> 4, lrow = lane & 15;                                  \
  const int m_base = ((tid >> 6) >> 1) * 112, n_base = ((tid >> 6) & 1) * 64;    \
  int sbase[7];                                                                  \
  _Pragma("unroll")                                                              \
  for (int mi = 0; mi < 7; ++mi) {                                               \
    int row = m_base + mi * 16 + lrow;                                           \
    sbase[mi] = (row / 56) * 58 + (row % 56);                                    \
  }                                                                              \
  int boff[4], bldsoff[4];                                                       \
  _Pragma("unroll")                                                              \
  for (int i = 0; i < 4; ++i) {                                                  \
    int c = i * 256 + tid;                                                       \
    int r = c >> 3;                                                              \
    boff[i] = r * 128 + ((c & 7) ^ (r & 7)) * 16;                                \
    bldsoff[i] = (i * 256 + (tid & ~63)) * 16;                                   \
  }                                                                              \
  i32x4 acc[7][4];                                                               \
  _Pragma("unroll")                                                              \
  for (int mi = 0; mi < 7; ++mi)                                                 \
    _Pragma("unroll")                                                            \
    for (int ni = 0; ni < 4; ++ni) acc[mi][ni] = (i32x4){0, 0, 0, 0};

// prologue: stage halo strip (linear LDS dest, inverse-swizzled source) + B tile kk=0
#define CONV_STAGE_PRO(STRIPSRC, WQ)                                             \
  _Pragma("unroll")                                                              \
  for (int it = 0; it < 11; ++it) {                                              \
    int u = it * 256 + tid;                                                      \
    if (u < STRIPC) {                                                            \
      int s = u >> 3, cc = u & 7;                                                \
      async16((STRIPSRC) + s * 128 + ((cc ^ (s & 7)) << 4),                      \
              smem + (it * 256 + (tid & ~63)) * 16);                             \
    }                                                                            \
  }                                                                              \
  _Pragma("unroll")                                                              \
  for (int i = 0; i < 4; ++i) async16((WQ) + boff[i], smem + BBASE + bldsoff[i]);\
  __syncthreads();

#define CONV_KLOOP2(WQ)                                                          \
  _Pragma("unroll")                                                              \
  for (int kk = 0; kk < 9; ++kk) {                                               \
    if (kk < 8) {                     /* prefetch next weight tile */            \
      const int kn = kk + 1;                                                     \
      char* nb = smem + BBASE + ((kn & 1) << 14);                                \
      _Pragma("unroll")                                                          \
      for (int i = 0; i < 4; ++i)                                                \
        async16((WQ) + kn * 16384 + boff[i], nb + bldsoff[i]);                   \
    }                                                                            \
    const char* Bs = smem + BBASE + ((kk & 1) << 14);                            \
    const int dkk = (kk / 3) * 58 + (kk % 3);                                    \
    int aaddr[7];                                                                \
    _Pragma("unroll")                                                            \
    for (int mi = 0; mi < 7; ++mi) {                                             \
      int s = sbase[mi] + dkk;                                                   \
      aaddr[mi] = (s << 7) + ((quad << 4) ^ ((s & 7) << 4));                     \
    }                                                                            \
    __builtin_amdgcn_s_setprio(1);                                               \
    _Pragma("unroll")                                                            \
    for (int j = 0; j < 2; ++j) {                                                \
      i32x4 af[7], bf[4];                                                        \
      _Pragma("unroll")                                                          \
      for (int mi = 0; mi < 7; ++mi)                                             \
        af[mi] = *(const i32x4*)(smem + (aaddr[mi] ^ (j << 6)));                 \
      _Pragma("unroll")                                                          \
      for (int ni = 0; ni < 4; ++ni) {                                           \
        int brow = n_base + ni * 16 + lrow;                                      \
        bf[ni] = *(const i32x4*)(Bs + brow * 128 +                               \
                                 (((j << 6) | (quad << 4)) ^ ((brow & 7) << 4)));\
      }                                                                          \
      _Pragma("unroll")                                                          \
      for (int mi = 0; mi < 7; ++mi)                                             \
        _Pragma("unroll")                                                        \
        for (int ni = 0; ni < 4; ++ni)                                           \
          acc[mi][ni] = __builtin_amdgcn_mfma_i32_16x16x64_i8(af[mi], bf[ni], acc[mi][ni], 0, 0, 0); \
    }                                                                            \
    __builtin_amdgcn_s_setprio(0);                                               \
    __syncthreads();                                                             \
  }

// ---------------- conv pass: q?p -> y i16 + stats (used for both convs) ----------------
// y target selectable per image: n < nsplit -> ylo[n], else yhi[n-nsplit]
__global__ __launch_bounds__(256, 2)
void k_conv(const unsigned char* __restrict__ act, const unsigned char* __restrict__ wq,
            short* __restrict__ ylo, short* __restrict__ yhi, int nsplit,
            float* __restrict__ stats) {
  __shared__ __align__(16) char smem[SMEMSZ];   // 44.5K strip + 32K B dbuf + 1K red
  const int bidx = ((blockIdx.x & 7) * 112) + (blockIdx.x >> 3);  // XCD swizzle (896=8*112)
  const int n = bidx / 14, br = bidx % 14;
  const unsigned char* strip = act + (size_t)n * PADB + (size_t)br * 4 * PADW * 128;
  CONV_SETUP2
  CONV_STAGE_PRO(strip, wq)
  CONV_KLOOP2(wq)
  short* yb = (n < nsplit ? ylo + (size_t)n * HWSZ * CH
                          : yhi + (size_t)(n - nsplit) * HWSZ * CH);
  const int pbase = br * BPIX;
  float lsum[4] = {0.f, 0.f, 0.f, 0.f}, lsq[4] = {0.f, 0.f, 0.f, 0.f};
#pragma unroll
  for (int mi = 0; mi < 7; ++mi) {
    int prow = pbase + m_base + mi * 16 + quad * 4;
#pragma unroll
    for (int ni = 0; ni < 4; ++ni) {
      int co = n_base + ni * 16 + lrow;
#pragma unroll
      for (int rg = 0; rg < 4; ++rg) {
        float v = (float)acc[mi][ni][rg];  // D: col=lane&15, row=quad*4+rg
        yb[(size_t)(prow + rg) * CH + co] = (short)fminf(fmaxf(v, -32767.f), 32767.f);
        lsum[ni] += v; lsq[ni] += v * v;
      }
    }
  }
#pragma unroll
  for (int ni = 0; ni < 4; ++ni) {
    lsum[ni] += __shfl_xor(lsum[ni], 16); lsum[ni] += __shfl_xor(lsum[ni], 32);
    lsq[ni]  += __shfl_xor(lsq[ni], 16);  lsq[ni]  += __shfl_xor(lsq[ni], 32);
  }
  __syncthreads();
  float* red = (float*)(smem + REDOFF);
  red[tid] = 0.f;
  __syncthreads();
  if (quad == 0) {
#pragma unroll
    for (int ni = 0; ni < 4; ++ni) {
      int co = n_base + ni * 16 + lrow;
      atomicAdd(&red[co], lsum[ni]);
      atomicAdd(&red[CH + co], lsq[ni]);
    }
  }
  __syncthreads();
  atomicAdd(&stats[tid], red[tid]);
}

// ---------------- BN1(inline) + act quant: y i16 -> q2p int8 padded (+halo zero) ----------------
// v2: 16 elems/thread (32 B loads, 16 B stores)
__global__ void k_bnq(const short* __restrict__ y, const float* __restrict__ stats,
                      const unsigned* __restrict__ abits, const float* __restrict__ g,
                      const float* __restrict__ b, unsigned char* __restrict__ q) {
  __shared__ float bnpS[256];
  int tid = threadIdx.x;
  bn_inline(tid, stats, abits, g, b, bnpS);
  if (blockIdx.x < 64) halo_zero(q + (size_t)blockIdx.x * PADB, tid);
  __syncthreads();
  size_t i = (size_t)blockIdx.x * 256 + tid;           // 16 elems/thread
  short8 v0 = ((const short8*)y)[i * 2];
  short8 v1 = ((const short8*)y)[i * 2 + 1];
  int c0 = (int)((i * 16) & (CH - 1));
  int pix = (int)(i >> 3);
  int n = pix / HWSZ, l = pix - n * HWSZ;
  int h = l / IMG, w = l - h * IMG;
  unsigned u[4] = {0u, 0u, 0u, 0u};
#pragma unroll
  for (int j = 0; j < 8; ++j) {
    float a0 = (float)v0[j] * bnpS[c0 + j] + bnpS[CH + c0 + j];
    float a1 = (float)v1[j] * bnpS[c0 + 8 + j] + bnpS[CH + c0 + 8 + j];
    unsigned q0 = (unsigned)(int)rintf(fminf(fmaxf(a0, 0.f), 1.f) * 15.f);
    unsigned q1 = (unsigned)(int)rintf(fminf(fmaxf(a1, 0.f), 1.f) * 15.f);
    u[j >> 2]       |= q0 << (8 * (j & 3));
    u[2 + (j >> 2)] |= q1 << (8 * (j & 3));
  }
  *(uint4*)(q + (size_t)n * PADB + ((h + 1) * PADW + (w + 1)) * 128 + c0) =
      (uint4){u[0], u[1], u[2], u[3]};
}

// ---------------- finale v2: BN2 + residual, wide y2 loads, full-channel tile ----------------
__global__ void k_fin(const short* __restrict__ ylo, const short* __restrict__ yhi, int nsplit,
                      const float* __restrict__ stats,
                      const unsigned* __restrict__ abits, const float* __restrict__ g,
                      const float* __restrict__ b, const float* __restrict__ x,
                      float* __restrict__ out, int img0) {
  __shared__ float bnpS[256];
  __shared__ float tile[128][33];
  int tx = threadIdx.x, ty = threadIdx.y, lin = ty * 32 + tx;
  bn_inline(lin, stats, abits, g, b, bnpS);
  __syncthreads();
  int n = img0 + blockIdx.z, p0 = blockIdx.x * 32;
  int p = lin >> 3, c0 = (lin & 7) * 16;
  const short* ybase = (n < nsplit ? ylo + (size_t)n * HWSZ * CH
                                   : yhi + (size_t)(n - nsplit) * HWSZ * CH);
  const short* ys = ybase + (size_t)(p0 + p) * CH + c0;   // 32 B/lane, 256 B/pixel
  short8 v0 = *(const short8*)ys;
  short8 v1 = *(const short8*)(ys + 8);
#pragma unroll
  for (int j = 0; j < 8; ++j) {
    tile[c0 + j][p]     = (float)v0[j] * bnpS[c0 + j]     + bnpS[CH + c0 + j];
    tile[c0 + 8 + j][p] = (float)v1[j] * bnpS[c0 + 8 + j] + bnpS[CH + c0 + 8 + j];
  }
  __syncthreads();
  const float* xs = x + (size_t)n * CH * HWSZ;
  float*       os = out + (size_t)n * CH * HWSZ;
#pragma unroll
  for (int r = 0; r < 16; ++r) {
    int c = ty + r * 8;
    size_t a = (size_t)c * HWSZ + p0 + tx;
    os[a] = tile[c][tx] + xs[a];                       // coalesced along p
  }
}

// ---------------- Plan B only: recompute conv2 for image 63 + BN2 + residual ----------------
__global__ __launch_bounds__(256, 2)
void k_conv_out63(const unsigned char* __restrict__ act, const unsigned char* __restrict__ wq,
                  const float* __restrict__ stats, const unsigned* __restrict__ abits,
                  const float* __restrict__ g, const float* __restrict__ b,
                  const float* __restrict__ x, float* __restrict__ out) {
  __shared__ __align__(16) char smem[SMEMSZ];
  __shared__ float bnpS[256];
  bn_inline(threadIdx.x, stats, abits, g, b, bnpS);
  const int br = blockIdx.x;          // 0..13, one image (63)
  const unsigned char* strip = act + (size_t)br * 4 * PADW * 128;
  CONV_SETUP2
  CONV_STAGE_PRO(strip, wq)
  CONV_KLOOP2(wq)
  __syncthreads();
  f16 (*tile)[228] = (f16(*)[228])smem;     // repurpose strip/B area (128*228*2 = 58368 B)
#pragma unroll
  for (int ni = 0; ni < 4; ++ni) {
    int co = n_base + ni * 16 + lrow;
    float sc = bnpS[co], sh = bnpS[CH + co];
#pragma unroll
    for (int mi = 0; mi < 7; ++mi) {
      int pr = m_base + mi * 16 + quad * 4;
#pragma unroll
      for (int rg = 0; rg < 4; ++rg)
        tile[co][pr + rg] = (f16)((float)acc[mi][ni][rg] * sc + sh);
    }
  }
  __syncthreads();
  int c = tid >> 1, seg = tid & 1;
  int pl0 = br * BPIX + seg * 112;
  size_t gb = ((size_t)63 * CH + c) * HWSZ + pl0;
  const float* xp = x + gb;
  float* op = out + gb;
  const f16* tr = &tile[c][seg * 112];
#pragma unroll
  for (int j = 0; j < 112; j += 4) {
    f32x4 xv = *(const f32x4*)(xp + j);
    f32x4 ov;
    ov[0] = (float)tr[j]     + xv[0];
    ov[1] = (float)tr[j + 1] + xv[1];
    ov[2] = (float)tr[j + 2] + xv[2];
    ov[3] = (float)tr[j + 3] + xv[3];
    *(f32x4*)(op + j) = ov;
  }
}

extern "C" void kernel_launch(void* const* d_in, const int* in_sizes, int n_in,
                              void* d_out, int out_size, void* d_ws, size_t ws_size,
                              hipStream_t stream) {
  (void)in_sizes; (void)n_in; (void)out_size;
  const float* x  = (const float*)d_in[0];
  const float* w1 = (const float*)d_in[1];
  const float* w2 = (const float*)d_in[2];
  const float* g1 = (const float*)d_in[3];
  const float* b1 = (const float*)d_in[4];
  const float* g2 = (const float*)d_in[5];
  const float* b2 = (const float*)d_in[6];
  float* out = (float*)d_out;

  char* dob = (char*)d_out;
  unsigned char* q1p = (unsigned char*)dob;            // padded i8 [0, 27.56M)
  unsigned char* q2p = (unsigned char*)dob;            // same region (q1p dead by then)
  short* y1 = (short*)(dob + YOFF);                    // i16 NHWC [27.56M, 78.94M)

  char* ws = (char*)d_ws;
  unsigned* alpha_bits = (unsigned*)ws;
  float* stats1 = (float*)(ws + 256);
  float* stats2 = (float*)(ws + 1280);

  hipMemsetAsync(ws, 0, 4608, stream);                 // alpha + stats
  k_wmax  <<<64, 256, 0, stream>>>(w1, w2, alpha_bits);

  if (ws_size >= 51679744u) {
    // ---- Plan A: everything conflict-free in ws ----
    unsigned char* wq1 = (unsigned char*)(ws + 4608);
    unsigned char* wq2 = (unsigned char*)(ws + 152064);
    short* y2 = (short*)(ws + 299520);
    k_wquant<<<2 * WELEMS / 256, 256, 0, stream>>>(w1, w2, alpha_bits, wq1, wq2);
    k_actq  <<<dim3(98, 1, 64), dim3(32, 8), 0, stream>>>(x, q1p);
    k_conv  <<<NBLK, 256, 0, stream>>>(q1p, wq1, y1, y1, 64, stats1);
    k_bnq   <<<NPIX * CH / 4096, 256, 0, stream>>>(y1, stats1, alpha_bits + 0, g1, b1, q2p);
    k_conv  <<<NBLK, 256, 0, stream>>>(q2p, wq2, y2, y2, 64, stats2);
    k_fin   <<<dim3(98, 1, 64), dim3(32, 8), 0, stream>>>(y2, y2, 64, stats2, alpha_bits + 1, g2, b2, x, out, 0);
    return;
  }

  // ---- Plan B family: wq1 parked in d_out (dead after conv1), wq2 in ws ----
  unsigned char* wq1 = (unsigned char*)(dob + WQ1OFF_B);
  unsigned char* wq2 = (unsigned char*)(ws + 4608);
  short* y2lo = (short*)(dob + Y2OFF_B);
  k_wquant<<<2 * WELEMS / 256, 256, 0, stream>>>(w1, w2, alpha_bits, wq1, wq2);
  k_actq  <<<dim3(98, 1, 64), dim3(32, 8), 0, stream>>>(x, q1p);
  k_conv  <<<NBLK, 256, 0, stream>>>(q1p, wq1, y1, y1, 64, stats1);
  k_bnq   <<<NPIX * CH / 4096, 256, 0, stream>>>(y1, stats1, alpha_bits + 0, g1, b1, q2p);

  if (ws_size >= 152064u + 32u * IMGB) {
    // ---- Plan B2: y2 imgs 0..31 in d_out top, imgs 32..63 in ws -> 2-launch finale ----
    short* y2hi = (short*)(ws + 152064);
    k_conv <<<NBLK, 256, 0, stream>>>(q2p, wq2, y2lo, y2hi, 32, stats2);
    k_fin <<<dim3(98, 1, 32), dim3(32, 8), 0, stream>>>(y2lo, y2hi, 32, stats2, alpha_bits + 1, g2, b2, x, out, 0);
    k_fin <<<dim3(98, 1, 32), dim3(32, 8), 0, stream>>>(y2lo, y2hi, 32, stats2, alpha_bits + 1, g2, b2, x, out, 32);
  } else if (ws_size >= 152064u + 16u * IMGB) {
    // ---- Plan B3: y2 imgs 0..47 in d_out top, imgs 48..63 in ws -> 3-launch finale ----
    short* y2hi = (short*)(ws + 152064);
    k_conv <<<NBLK, 256, 0, stream>>>(q2p, wq2, y2lo, y2hi, 48, stats2);
    k_fin <<<dim3(98, 1, 32), dim3(32, 8), 0, stream>>>(y2lo, y2hi, 48, stats2, alpha_bits + 1, g2, b2, x, out, 0);
    k_fin <<<dim3(98, 1, 16), dim3(32, 8), 0, stream>>>(y2lo, y2hi, 48, stats2, alpha_bits + 1, g2, b2, x, out, 32);
    k_fin <<<dim3(98, 1, 16), dim3(32, 8), 0, stream>>>(y2lo, y2hi, 48, stats2, alpha_bits + 1, g2, b2, x, out, 48);
  } else {
    // ---- Plan B classic (proven ws budget 582,656 B) ----
    unsigned char* q63p = (unsigned char*)(ws + 152064); // 430,592 B
    k_conv <<<NBLK, 256, 0, stream>>>(q2p, wq2, y2lo, y2lo, 64, stats2);
    // in-place finale: out[n] destroys y2[2n-64, 2n-63]; batch [a,b] safe iff 2b+2 <= 64+a
    hipMemcpyAsync(q63p, q2p + (size_t)63 * PADB, PADB, hipMemcpyDeviceToDevice, stream);
    k_fin <<<dim3(98, 1, 32), dim3(32, 8), 0, stream>>>(y2lo, y2lo, 64, stats2, alpha_bits + 1, g2, b2, x, out, 0);
    k_fin <<<dim3(98, 1, 16), dim3(32, 8), 0, stream>>>(y2lo, y2lo, 64, stats2, alpha_bits + 1, g2, b2, x, out, 32);
    k_fin <<<dim3(98, 1,  8), dim3(32, 8), 0, stream>>>(y2lo, y2lo, 64, stats2, alpha_bits + 1, g2, b2, x, out, 48);
    k_fin <<<dim3(98, 1,  4), dim3(32, 8), 0, stream>>>(y2lo, y2lo, 64, stats2, alpha_bits + 1, g2, b2, x, out, 56);
    k_fin <<<dim3(98, 1,  2), dim3(32, 8), 0, stream>>>(y2lo, y2lo, 64, stats2, alpha_bits + 1, g2, b2, x, out, 60);
    k_fin <<<dim3(98, 1,  1), dim3(32, 8), 0, stream>>>(y2lo, y2lo, 64, stats2, alpha_bits + 1, g2, b2, x, out, 62);
    k_conv_out63<<<14, 256, 0, stream>>>(q63p, wq2, stats2, alpha_bits + 1, g2, b2, x, out);
  }
}